// Round 2
// baseline (519.054 us; speedup 1.0000x reference)
//
#include <hip/hip_runtime.h>
#include <hip/hip_bf16.h>

// ---------------------------------------------------------------------------
// rWindowAttention fused kernel (MI355X / gfx950)
//
// Shapes: B=1024, N=256 (= 4 blocks x 64), C=128, H=4, Dh=32.
// Strategy: one workgroup (512 thr = 8 waves) per batch; all five matmuls on
// v_mfma_f32_32x32x16_bf16. Attention over all 256 keys with -1e30 bias mask
// for the excluded 64-block (== reference's "other" gather + softmax zeros).
//
// MFMA 32x32x16 bf16 fragment maps used throughout (lane = tid&63, lq=lane&31,
// lh=lane>>5):
//   A[row][k]  : row = lq, k = 8*lh + j   (8 contiguous k per lane, 16B)
//   B[k][col]  : col = lq, k = 8*lh + j
//   C/D        : col = lq, row = (r&3) + 8*(r>>2) + 4*lh   (r = 0..15)
//
// Per head h:
//   q,k via swapped GEMM  D = (W^T)(x^T): row=d, col=n  -> 8B pair-writes give
//       q_lds[n][d], k_lds[n][d] (d contiguous = what QK^T fragments read).
//   v via normal GEMM     D = x . W     : row=n, col=d  -> pair-writes give
//       vt_lds[d][key] (key contiguous = what PV A-fragments read).
//   S^T = K . Q^T (+bias C-init): D row=key, col=q. Softmax per q = local
//       reduce over 128 regs + shfl_xor(32) (lanes L, L+32 hold the two key
//       halves of the same q column).
//   P -> PV B-frag: pack key-pairs to bf16x2 words pk[m] (keys 8*(m>>1)+4*lh+
//       2*(m&1)+{0,1}); for 16-key step s the frag words c0..c3 are
//       (c0,c2)=permlane32_swap(pk[4s],pk[4s+2]), (c1,c3)=swap(pk[4s+1],pk[4s+3]).
//   out_h[n][d] per wave (private rows) -> partial proj accumulated in VGPRs
//       yacc[4] (f32x16) across heads; + proj_b and fp32 store at the end.
// ---------------------------------------------------------------------------

typedef float  f32x16 __attribute__((ext_vector_type(16)));
typedef float  f32x4_ __attribute__((ext_vector_type(4)));
typedef __bf16 bf16x8 __attribute__((ext_vector_type(8)));
typedef __bf16 bf16x2 __attribute__((ext_vector_type(2)));
typedef unsigned int  uint32x4_ __attribute__((ext_vector_type(4)));
typedef unsigned int  uint32x2_ __attribute__((ext_vector_type(2)));

#define MFMA32(a, b, c) __builtin_amdgcn_mfma_f32_32x32x16_bf16((a), (b), (c), 0, 0, 0)

static __device__ __forceinline__ unsigned int packbf2(float a, float b) {
  bf16x2 t = { (__bf16)a, (__bf16)b };
  return __builtin_bit_cast(unsigned int, t);
}
// v_permlane32_swap_b32: new_a = [a_lo | b_lo], new_b = [a_hi | b_hi]
static __device__ __forceinline__ void plswap(unsigned int &a, unsigned int &b) {
  asm volatile("v_permlane32_swap_b32 %0, %1" : "+v"(a), "+v"(b));
}

// LDS byte offsets (total 128 KiB)
#define XS_OFF 0        // x   bf16 [256][128], 256B rows, swizzle (n&7)<<4
#define QL_OFF 65536    // q   bf16 [256][32],  64B rows, swizzle ((n>>1)&3)<<4
#define KL_OFF 81920    // k   bf16 [256][32]
#define VT_OFF 98304    // v^T bf16 [32][256], 512B rows, swizzle (d&7)<<4
#define OH_OFF 114688   // out_h bf16 [256][32]

static __device__ __forceinline__ int swzA(int row, int off) {  // 64B rows
  return (row << 6) + (off ^ (((row >> 1) & 3) << 4));
}
static __device__ __forceinline__ int swzX(int row, int off) {  // 256B rows
  return (row << 8) + (off ^ ((row & 7) << 4));
}
static __device__ __forceinline__ int swzV(int row, int off) {  // 512B rows
  return (row << 9) + (off ^ ((row & 7) << 4));
}

__global__ void prep_kernel(const float* __restrict__ qw, const float* __restrict__ kvw,
                            const float* __restrict__ pw, const float* __restrict__ rpb,
                            const int* __restrict__ relidx,
                            float* __restrict__ biasT, unsigned short* __restrict__ qwt,
                            unsigned short* __restrict__ kwt, unsigned short* __restrict__ vwt,
                            unsigned short* __restrict__ pwt) {
  int gid = blockIdx.x * 256 + threadIdx.x;
  if (gid < 262144) {
    // biasT[i][h][ql][key], f32, masked block -> -1e30
    int key = gid & 255;
    int ql  = (gid >> 8) & 63;
    int h   = (gid >> 14) & 3;
    int i   = gid >> 16;
    float v;
    if ((key >> 6) == i) v = -1.0e30f;
    else                 v = rpb[relidx[(i * 64 + ql) * 256 + key] * 4 + h];
    biasT[gid] = v;
  } else {
    int wid = gid - 262144;
    if (wid < 16384) {  // transposed bf16 weights [cout][cin]
      int cin = wid & 127, cout = wid >> 7;
      qwt[wid] = __builtin_bit_cast(unsigned short, (__bf16)(qw[cin * 128 + cout] * 0.17677669529663687f));
      kwt[wid] = __builtin_bit_cast(unsigned short, (__bf16)(kvw[cin * 256 + cout]));
      vwt[wid] = __builtin_bit_cast(unsigned short, (__bf16)(kvw[cin * 256 + 128 + cout]));
      pwt[wid] = __builtin_bit_cast(unsigned short, (__bf16)(pw[cin * 128 + cout]));
    }
  }
}

__global__ __launch_bounds__(512, 2) void fused_attn(
    const float* __restrict__ x, const float* __restrict__ biasT,
    const unsigned short* __restrict__ qwt, const unsigned short* __restrict__ kwt,
    const unsigned short* __restrict__ vwt, const unsigned short* __restrict__ pwt,
    const float* __restrict__ proj_b, float* __restrict__ out) {
  __shared__ __align__(16) char smem[131072];
  const int tid  = threadIdx.x;
  const int w    = tid >> 6;    // wave id: owns q rows [32w, 32w+32)
  const int lane = tid & 63;
  const int lq   = lane & 31;
  const int lh   = lane >> 5;
  const int b    = blockIdx.x;

  // ---- stage x -> xs bf16 (coalesced float4 loads, 8B LDS writes) ----
  const float* xb = x + (size_t)b * (256 * 128);
  #pragma unroll
  for (int it = 0; it < 16; ++it) {
    int idx = it * 512 + tid;              // float4 index; row n = idx>>5, col4 = idx&31
    f32x4_ v = ((const f32x4_*)xb)[idx];
    int n = idx >> 5, c4 = idx & 31;
    uint32x2_ wv = { packbf2(v[0], v[1]), packbf2(v[2], v[3]) };
    *(uint32x2_*)(smem + XS_OFF + swzX(n, c4 * 8)) = wv;
  }
  __syncthreads();

  f32x16 yacc[4];
  #pragma unroll
  for (int nt = 0; nt < 4; ++nt)
    #pragma unroll
    for (int r = 0; r < 16; ++r) yacc[nt][r] = 0.0f;

  for (int h = 0; h < 4; ++h) {
    // ---- GEMMs: q,k (swapped), v (normal); all share the xs fragment ----
    f32x16 qa, ka, va;
    #pragma unroll
    for (int r = 0; r < 16; ++r) { qa[r] = 0.0f; ka[r] = 0.0f; va[r] = 0.0f; }
    const int wrow = h * 32 + lq;
    #pragma unroll
    for (int ks = 0; ks < 8; ++ks) {
      bf16x8 xf = *(const bf16x8*)(smem + XS_OFF + swzX(w * 32 + lq, ks * 32 + lh * 16));
      bf16x8 wq = *(const bf16x8*)(qwt + wrow * 128 + ks * 16 + lh * 8);
      bf16x8 wk = *(const bf16x8*)(kwt + wrow * 128 + ks * 16 + lh * 8);
      bf16x8 wv = *(const bf16x8*)(vwt + wrow * 128 + ks * 16 + lh * 8);
      qa = MFMA32(wq, xf, qa);   // D row=d, col=n
      ka = MFMA32(wk, xf, ka);
      va = MFMA32(xf, wv, va);   // D row=key, col=d
    }
    #pragma unroll
    for (int g = 0; g < 4; ++g) {
      uint32x2_ q2 = { packbf2(qa[4*g+0], qa[4*g+1]), packbf2(qa[4*g+2], qa[4*g+3]) };
      *(uint32x2_*)(smem + QL_OFF + swzA(w * 32 + lq, g * 16 + lh * 8)) = q2;
      uint32x2_ k2 = { packbf2(ka[4*g+0], ka[4*g+1]), packbf2(ka[4*g+2], ka[4*g+3]) };
      *(uint32x2_*)(smem + KL_OFF + swzA(w * 32 + lq, g * 16 + lh * 8)) = k2;
      uint32x2_ v2 = { packbf2(va[4*g+0], va[4*g+1]), packbf2(va[4*g+2], va[4*g+3]) };
      *(uint32x2_*)(smem + VT_OFF + swzV(lq, w * 64 + g * 16 + lh * 8)) = v2;
    }
    __syncthreads();

    // ---- attention for wave's 32 q rows ----
    const int iblk   = w >> 1;
    const int qlocal = (w & 1) * 32 + lq;
    const float* biasW = biasT + (((iblk * 4 + h) * 64 + qlocal) * 256);
    bf16x8 qb0 = *(const bf16x8*)(smem + QL_OFF + swzA(w * 32 + lq, lh * 16));
    bf16x8 qb1 = *(const bf16x8*)(smem + QL_OFF + swzA(w * 32 + lq, 32 + lh * 16));

    f32x16 S[8];
    #pragma unroll
    for (int kt = 0; kt < 8; ++kt) {
      f32x16 c;
      #pragma unroll
      for (int g = 0; g < 4; ++g) {   // C-init = bias (keys 32kt+4lh+8g+{0..3})
        f32x4_ bv = *(const f32x4_*)(biasW + kt * 32 + lh * 4 + g * 8);
        c[4*g+0] = bv[0]; c[4*g+1] = bv[1]; c[4*g+2] = bv[2]; c[4*g+3] = bv[3];
      }
      bf16x8 ka0 = *(const bf16x8*)(smem + KL_OFF + swzA(kt * 32 + lq, lh * 16));
      bf16x8 ka1 = *(const bf16x8*)(smem + KL_OFF + swzA(kt * 32 + lq, 32 + lh * 16));
      c = MFMA32(ka0, qb0, c);
      c = MFMA32(ka1, qb1, c);
      S[kt] = c;
    }
    // softmax over keys (per q column; lanes L and L+32 hold the two halves)
    float m = -3.0e38f;
    #pragma unroll
    for (int kt = 0; kt < 8; ++kt)
      #pragma unroll
      for (int r = 0; r < 16; ++r) m = fmaxf(m, S[kt][r]);
    m = fmaxf(m, __shfl_xor(m, 32, 64));
    float l = 0.0f;
    #pragma unroll
    for (int kt = 0; kt < 8; ++kt)
      #pragma unroll
      for (int r = 0; r < 16; ++r) { float e = __expf(S[kt][r] - m); S[kt][r] = e; l += e; }
    l += __shfl_xor(l, 32, 64);
    float linv = 1.0f / l;

    // ---- PV: out[d][q] = sum_key vt[d][key] * P[key][q] ----
    f32x16 pv;
    #pragma unroll
    for (int r = 0; r < 16; ++r) pv[r] = 0.0f;
    #pragma unroll
    for (int kt = 0; kt < 8; ++kt) {
      unsigned int pk0 = packbf2(S[kt][0],  S[kt][1]);
      unsigned int pk1 = packbf2(S[kt][2],  S[kt][3]);
      unsigned int pk2 = packbf2(S[kt][4],  S[kt][5]);
      unsigned int pk3 = packbf2(S[kt][6],  S[kt][7]);
      unsigned int pk4 = packbf2(S[kt][8],  S[kt][9]);
      unsigned int pk5 = packbf2(S[kt][10], S[kt][11]);
      unsigned int pk6 = packbf2(S[kt][12], S[kt][13]);
      unsigned int pk7 = packbf2(S[kt][14], S[kt][15]);
      plswap(pk0, pk2); plswap(pk1, pk3);   // 16-key step 0: frag = {pk0,pk1,pk2,pk3}
      plswap(pk4, pk6); plswap(pk5, pk7);   // 16-key step 1: frag = {pk4,pk5,pk6,pk7}
      uint32x4_ f0 = { pk0, pk1, pk2, pk3 };
      uint32x4_ f1 = { pk4, pk5, pk6, pk7 };
      bf16x8 b0 = __builtin_bit_cast(bf16x8, f0);
      bf16x8 b1 = __builtin_bit_cast(bf16x8, f1);
      bf16x8 va0 = *(const bf16x8*)(smem + VT_OFF + swzV(lq, kt * 64 + lh * 16));
      bf16x8 va1 = *(const bf16x8*)(smem + VT_OFF + swzV(lq, kt * 64 + 32 + lh * 16));
      pv = MFMA32(va0, b0, pv);
      pv = MFMA32(va1, b1, pv);
    }
    // normalize, write out_h[n][d] (wave-private rows; no barrier needed)
    #pragma unroll
    for (int g = 0; g < 4; ++g) {
      uint32x2_ o2 = { packbf2(pv[4*g+0] * linv, pv[4*g+1] * linv),
                       packbf2(pv[4*g+2] * linv, pv[4*g+3] * linv) };
      *(uint32x2_*)(smem + OH_OFF + swzA(w * 32 + lq, g * 16 + lh * 8)) = o2;
    }
    __syncthreads();   // k/q/vt consumed; next head may overwrite

    // ---- partial proj: yacc += out_h(:, h*32:+32) @ pwt rows h*32:+32 ----
    bf16x8 a0 = *(const bf16x8*)(smem + OH_OFF + swzA(w * 32 + lq, lh * 16));
    bf16x8 a1 = *(const bf16x8*)(smem + OH_OFF + swzA(w * 32 + lq, 32 + lh * 16));
    #pragma unroll
    for (int nt = 0; nt < 4; ++nt) {
      bf16x8 pb0 = *(const bf16x8*)(pwt + (nt * 32 + lq) * 128 + h * 32 + lh * 8);
      bf16x8 pb1 = *(const bf16x8*)(pwt + (nt * 32 + lq) * 128 + h * 32 + 16 + lh * 8);
      yacc[nt] = MFMA32(a0, pb0, yacc[nt]);
      yacc[nt] = MFMA32(a1, pb1, yacc[nt]);
    }
  }

  // ---- epilogue: + proj_b, fp32 store ----
  float* yb = out + (size_t)b * (256 * 128);
  #pragma unroll
  for (int nt = 0; nt < 4; ++nt) {
    float pbv = proj_b[nt * 32 + lq];
    #pragma unroll
    for (int g = 0; g < 4; ++g)
      #pragma unroll
      for (int r2 = 0; r2 < 4; ++r2) {
        int n = w * 32 + 8 * g + 4 * lh + r2;
        yb[n * 128 + nt * 32 + lq] = yacc[nt][4 * g + r2] + pbv;
      }
  }
}

extern "C" void kernel_launch(void* const* d_in, const int* in_sizes, int n_in,
                              void* d_out, int out_size, void* d_ws, size_t ws_size,
                              hipStream_t stream) {
  (void)in_sizes; (void)n_in; (void)out_size; (void)ws_size;
  const float* x      = (const float*)d_in[0];
  const float* qw     = (const float*)d_in[1];
  const float* kvw    = (const float*)d_in[2];
  const float* pw     = (const float*)d_in[3];
  const float* pb     = (const float*)d_in[4];
  const float* rpb    = (const float*)d_in[5];
  const int*   relidx = (const int*)d_in[6];
  float* out = (float*)d_out;

  char* ws = (char*)d_ws;              // needs ~1.18 MiB of workspace
  float* biasT          = (float*)ws;                         // 1 MiB
  unsigned short* qwt   = (unsigned short*)(ws + 1048576);    // 32 KiB each
  unsigned short* kwt   = (unsigned short*)(ws + 1048576 + 32768);
  unsigned short* vwt   = (unsigned short*)(ws + 1048576 + 65536);
  unsigned short* pwt   = (unsigned short*)(ws + 1048576 + 98304);

  prep_kernel<<<dim3(1088), dim3(256), 0, stream>>>(qw, kvw, pw, rpb, relidx,
                                                    biasT, qwt, kwt, vwt, pwt);
  fused_attn<<<dim3(1024), dim3(512), 0, stream>>>(x, biasT, qwt, kwt, vwt, pwt, pb, out);
}